// Round 9
// baseline (1045.612 us; speedup 1.0000x reference)
//
#include <hip/hip_runtime.h>
#include <cstdint>
#include <cstddef>

#define NV 200000
#define NT 800000
#define ROWS 48
#define MBLK 4167   // ceil(200000/48); 4167*48 = 200016, tail guarded
#define NBLK 3125   // 3125*256 = 800000 exactly (tet kernels)

typedef unsigned int u32;
typedef unsigned long long u64;

typedef __attribute__((ext_vector_type(8))) _Float16 half8;
typedef __attribute__((ext_vector_type(4))) float f32x4;
#define MFMA16F __builtin_amdgcn_mfma_f32_16x16x32_f16

// ---------------- marching-tets tables ----------------
__constant__ int c_tri[16][6] = {
  {-1,-1,-1,-1,-1,-1},{1,0,2,-1,-1,-1},{4,0,3,-1,-1,-1},{1,4,2,1,3,4},
  {3,1,5,-1,-1,-1},{2,3,0,2,5,3},{1,4,0,1,5,4},{4,2,5,-1,-1,-1},
  {4,5,2,-1,-1,-1},{4,1,0,4,5,1},{3,2,0,3,5,2},{1,3,5,-1,-1,-1},
  {4,1,2,4,3,1},{3,0,4,-1,-1,-1},{2,0,1,-1,-1,-1},{-1,-1,-1,-1,-1,-1}};
__constant__ int c_ntri[16] = {0,1,1,2,1,2,2,1,1,2,2,1,2,1,1,0};
__constant__ int c_be[12] = {0,1,0,2,0,3,1,2,1,3,2,3};

// ---------------- fp16 Dekker 2-way split: x ~= h + m*2^-11 ----------------
__device__ __forceinline__ void split2(float x, _Float16& h, _Float16& m){
  h = (_Float16)x;
  const float r = x - (float)h;
  m = (_Float16)(r * 2048.0f);
}

// ---------------- weight split prep + workspace zeroing (fused memsets) ----------------
__global__ void split_weights(const float* __restrict__ w0, const float* __restrict__ w1,
                              const float* __restrict__ w2, const float* __restrict__ w3,
                              _Float16* __restrict__ wp,
                              u32* __restrict__ cnt_z, u32* __restrict__ cur_z)
{
  const int idx = blockIdx.x*256 + threadIdx.x;   // 0..204799
  if (idx < NV){ cnt_z[idx] = 0u; cur_z[idx] = 0u; }
  int base, k, n, psz;
  float val;
  if (idx < 8192){                                  // layer0: K=27 padded to 32
    base = 0; psz = 8192; k = idx >> 8; n = idx & 255;
    val = (k < 27) ? w0[k*256 + n] : 0.f;
  } else {
    int r = idx - 8192;
    const int l = r >> 16;                          // 0..2 -> layers 1..3
    r &= 65535;
    k = r >> 8; n = r & 255; psz = 65536;
    base = 16384 + l*131072;
    const float* w = (l==0) ? w1 : (l==1) ? w2 : w3;
    val = w[k*256 + n];
  }
  _Float16 h, m; split2(val, h, m);
  const int c = k >> 5, kk = k & 31;
  const int off = (c*256 + n)*32 + kk;
  wp[base + off] = h;
  wp[base + psz + off] = m;
}

// ---------------- MFMA MLP: block = 48 rows x 256 cols, 512 thr, 3 blocks/CU ----------------
template<int NC, bool LAST>
__device__ __forceinline__ void layer_run(
    const _Float16* __restrict__ Wl, const float* __restrict__ Bv,
    const float* __restrict__ wfv,
    _Float16 (*Af)[ROWS][264], float (*part)[8],
    int lane, int wv)
{
  const int l15 = lane & 15, q = lane >> 4;
  const int col0 = wv * 32;
  f32x4 g0[3][2], g1[3][2];
#pragma unroll
  for (int i=0;i<3;i++)
#pragma unroll
    for (int j=0;j<2;j++){ g0[i][j] = (f32x4){0.f,0.f,0.f,0.f}; g1[i][j] = (f32x4){0.f,0.f,0.f,0.f}; }

  const _Float16* bp = Wl + (u32)((col0 + l15)*32 + q*8);
  half8 bA[2][2], bB[2][2];

  auto loadB = [&](int c, half8 (*dst)[2]){
#pragma unroll
    for (int p=0;p<2;p++)
#pragma unroll
      for (int nt=0;nt<2;nt++)
        dst[p][nt] = *(const half8*)(bp + (p*NC + c)*8192 + nt*512);
  };
  auto compute = [&](int c, const half8 (*bb)[2]){
#pragma unroll
    for (int mt=0;mt<3;mt++){
      const _Float16* ap = &Af[0][mt*16 + l15][c*32 + q*8];
      const half8 ah = *(const half8*)(ap);
      const half8 am = *(const half8*)(ap + ROWS*264);
#pragma unroll
      for (int nt=0;nt<2;nt++){
        g0[mt][nt] = MFMA16F(ah, bb[0][nt], g0[mt][nt], 0,0,0);   // h*h
        g1[mt][nt] = MFMA16F(ah, bb[1][nt], g1[mt][nt], 0,0,0);   // h*m'
        g1[mt][nt] = MFMA16F(am, bb[0][nt], g1[mt][nt], 0,0,0);   // m'*h
      }
    }
  };

  loadB(0, bA);
  if (NC == 1){
    compute(0, bA);
  } else {
#pragma unroll 1
    for (int ch=0; ch<NC/2; ch++){
      const int c0 = 2*ch;
      loadB(c0+1, bB);
      compute(c0, bA);
      if (c0+2 < NC) loadB(c0+2, bA);
      compute(c0+1, bB);
    }
  }
  __syncthreads();

  const float S = 4.8828125e-4f;         // 2^-11
  if (!LAST){
#pragma unroll
    for (int nt=0;nt<2;nt++){
      const int col = col0 + nt*16 + l15;
      const float bias = Bv[col];
#pragma unroll
      for (int mt=0;mt<3;mt++)
#pragma unroll
        for (int reg=0;reg<4;reg++){
          const int row = mt*16 + q*4 + reg;
          const float v = fmaxf(g0[mt][nt][reg] + S*g1[mt][nt][reg] + bias, 0.f);
          _Float16 h,m; split2(v,h,m);
          Af[0][row][col] = h; Af[1][row][col] = m;
        }
    }
  } else {
    float pr[3][4];
#pragma unroll
    for (int mt=0;mt<3;mt++)
#pragma unroll
      for (int reg=0;reg<4;reg++) pr[mt][reg] = 0.f;
#pragma unroll
    for (int nt=0;nt<2;nt++){
      const int col = col0 + nt*16 + l15;
      const float bias = Bv[col];
      const float w = wfv[col];
#pragma unroll
      for (int mt=0;mt<3;mt++)
#pragma unroll
        for (int reg=0;reg<4;reg++)
          pr[mt][reg] += fmaxf(g0[mt][nt][reg] + S*g1[mt][nt][reg] + bias, 0.f) * w;
    }
#pragma unroll
    for (int s=1;s<16;s<<=1)
#pragma unroll
      for (int mt=0;mt<3;mt++)
#pragma unroll
        for (int reg=0;reg<4;reg++)
          pr[mt][reg] += __shfl_xor(pr[mt][reg], s, 64);
    if (l15 == 0){
#pragma unroll
      for (int mt=0;mt<3;mt++)
#pragma unroll
        for (int reg=0;reg<4;reg++)
          part[mt*16 + q*4 + reg][wv] = pr[mt][reg];
    }
  }
  __syncthreads();
}

__global__ __launch_bounds__(512,6) void mlp_mfma(
    const float* __restrict__ pos, const _Float16* __restrict__ wp,
    const float* __restrict__ b0, const float* __restrict__ b1,
    const float* __restrict__ b2, const float* __restrict__ b3,
    const float* __restrict__ wf, const float* __restrict__ bf,
    float* __restrict__ sdf)
{
  __shared__ _Float16 Af[2][ROWS][264];    // 50,688 B
  __shared__ float part[ROWS][8];          // 1,536 B -> 52.2 KB total = 3 blocks/CU
  const int tid = threadIdx.x;
  const int lane = tid & 63, wv = tid >> 6;
  const int row0 = blockIdx.x * ROWS;

  // layer0 input: positional encoding + fp16x2 split, K padded 27->32 (1536 = 3*512)
#pragma unroll
  for (int it=0; it<3; it++){
    const int idx = it*512 + tid;
    const int r = idx % ROWS, f = idx / ROWS;
    const int grow = row0 + r;
    float val = 0.f;
    if (f < 3){
      val = (grow < NV) ? pos[grow*3 + f] : 0.f;
    } else if (f < 27){
      const int g = (f-3)/6, rem = (f-3)%6;
      const int d = rem % 3;
      const float x = (grow < NV) ? pos[grow*3 + d] : 0.f;
      const float fr = (float)(1 << g) * 3.14159265358979323846f;
      val = (rem < 3) ? sinf(fr*x) : cosf(fr*x);
    }
    _Float16 h,m; split2(val,h,m);
    Af[0][r][f] = h; Af[1][r][f] = m;
  }
  __syncthreads();

  layer_run<1,false>(wp + 0,      b0, nullptr, Af, part, lane, wv);
  layer_run<8,false>(wp + 16384,  b1, nullptr, Af, part, lane, wv);
  layer_run<8,false>(wp + 147456, b2, nullptr, Af, part, lane, wv);
  layer_run<8,true >(wp + 278528, b3, wf,      Af, part, lane, wv);

  if (tid < ROWS && row0 + tid < NV){
    float s = 0.f;
#pragma unroll
    for (int w=0; w<8; w++) s += part[tid][w];
    sdf[row0 + tid] = s + bf[0];
  }
}

// ---------------- scan helpers ----------------
__device__ __forceinline__ u32 wave_scan_incl(u32 v, int lane){
#pragma unroll
  for (int s=1;s<64;s<<=1){
    const u32 y = __shfl_up(v, s, 64);
    if (lane >= s) v += y;
  }
  return v;
}
// 256-thread block scan via wave shuffles (1 barrier)
__device__ __forceinline__ u32 block_scan_fast(u32 v, u32* sh4, int tid){
  const int lane = tid & 63, wv = tid >> 6;
  const u32 incl = wave_scan_incl(v, lane);
  if (lane == 63) sh4[wv] = incl;
  __syncthreads();
  u32 base = 0;
#pragma unroll
  for (int w=0;w<3;w++) if (w < wv) base += sh4[w];
  return incl + base;
}
// legacy LDS-ladder scans (used in low-traffic scan kernels)
__device__ __forceinline__ u32 bscan_u32(u32 v, u32* sh, int tid){
  sh[tid]=v; __syncthreads();
#pragma unroll
  for (int s=1;s<256;s<<=1){
    const u32 y = (tid>=s) ? sh[tid-s] : 0u;
    __syncthreads();
    sh[tid] += y;
    __syncthreads();
  }
  return sh[tid];
}
__device__ __forceinline__ u64 bscan_u64(u64 v, u64* sh, int tid){
  sh[tid]=v; __syncthreads();
#pragma unroll
  for (int s=1;s<256;s<<=1){
    const u64 y = (tid>=s) ? sh[tid-s] : 0ull;
    __syncthreads();
    sh[tid] += y;
    __syncthreads();
  }
  return sh[tid];
}

// ---------------- tet pass 1: codes, in-block stable (n1,n2) scan, bucket counts ----------------
__global__ void tet_count(const int* __restrict__ tet, const float* __restrict__ sdf,
    unsigned char* __restrict__ codes, u32* __restrict__ tscan, u32* __restrict__ tsum,
    u32* __restrict__ cnt)
{
  __shared__ u32 sh4[4];
  const int tid = threadIdx.x;
  const int t = blockIdx.x*256 + tid;
  const int4 v = *(const int4*)(&tet[4*t]);
  const int o0 = sdf[v.x] > 0.f;
  const int o1 = sdf[v.y] > 0.f;
  const int o2 = sdf[v.z] > 0.f;
  const int o3 = sdf[v.w] > 0.f;
  const int code = o0 | (o1<<1) | (o2<<2) | (o3<<3);
  codes[t] = (unsigned char)code;
  const int nt = c_ntri[code];
  if (nt > 0){
    const int vv[4] = {v.x, v.y, v.z, v.w};
    const int oc[4] = {o0,o1,o2,o3};
#pragma unroll
    for (int e=0;e<6;e++){
      const int ia = c_be[2*e], ib = c_be[2*e+1];
      if (oc[ia] != oc[ib]){
        const int p = vv[ia], q = vv[ib];
        const int lo = p<q ? p : q;
        atomicAdd(&cnt[lo], 1u);
      }
    }
  }
  const u32 my = (u32)(nt==1) | ((u32)(nt==2)<<16);
  const u32 incl = block_scan_fast(my, sh4, tid);
  tscan[t] = incl - my;
  if (tid == 255) tsum[blockIdx.x] = incl;
}

// ---------------- mid-level scans (fused): blocks 0..195 cnt-segments; block 196 tsum scan ----------------
__global__ void scan_mid(const u32* __restrict__ cnt, u32* __restrict__ cntE,
                         u32* __restrict__ bsum, const u32* __restrict__ tsum,
                         u64* __restrict__ tsumE, u32* __restrict__ meta)
{
  __shared__ u32 sh[256];
  __shared__ u64 sh64[256];
  const int tid = threadIdx.x;
  if (blockIdx.x < 196){
    const int base = blockIdx.x*1024 + tid*4;
    u32 v[4]; u32 tot=0;
#pragma unroll
    for (int i=0;i<4;i++){
      const int idx = base+i;
      v[i] = (idx<NV) ? cnt[idx] : 0u;
      tot += v[i];
    }
    const u32 incl = bscan_u32(tot, sh, tid);
    u32 run = incl - tot;
#pragma unroll
    for (int i=0;i<4;i++){
      const int idx = base+i;
      if (idx<NV) cntE[idx] = run;
      run += v[i];
    }
    if (tid==255) bsum[blockIdx.x] = incl;
  } else {
    u64 loc[13]; u64 tot = 0ull;
#pragma unroll
    for (int i=0;i<13;i++){
      const int idx = tid*13 + i;
      const u32 p = (idx < NBLK) ? tsum[idx] : 0u;
      const u64 u = (u64)(p & 0xffffu) | ((u64)(p >> 16) << 32);
      loc[i] = u; tot += u;
    }
    const u64 incl = bscan_u64(tot, sh64, tid);
    u64 run = incl - tot;
#pragma unroll
    for (int i=0;i<13;i++){
      const int idx = tid*13 + i;
      if (idx < NBLK) tsumE[idx] = run;
      run += loc[i];
    }
    if (tid == 255){ meta[0] = (u32)(incl & 0xffffffffull); meta[1] = (u32)(incl >> 32); }
  }
}

// ---------------- top-level scan of bsum[196], in place -> exclusive ----------------
__global__ void scan_top(u32* __restrict__ arr, u32* __restrict__ meta, int slot)
{
  __shared__ u32 sh[256];
  const int tid = threadIdx.x;
  const u32 v = (tid < 196) ? arr[tid] : 0u;
  const u32 incl = bscan_u32(v, sh, tid);
  if (tid < 196) arr[tid] = incl - v;
  if (tid == 195) meta[slot] = incl;
}

// ---------------- fill pass ----------------
__global__ void fill_edges(const int* __restrict__ tet, const unsigned char* __restrict__ codes,
    const u32* __restrict__ cntE, const u32* __restrict__ bsum,
    u32* __restrict__ cur, int* __restrict__ ehi, int ecap)
{
  const int t = blockIdx.x*256 + threadIdx.x;
  const int code = codes[t];
  if (c_ntri[code] == 0) return;
  const int4 v = *(const int4*)(&tet[4*t]);
  const int vv[4]={v.x,v.y,v.z,v.w};
  const int oc[4]={code&1,(code>>1)&1,(code>>2)&1,(code>>3)&1};
#pragma unroll
  for (int e=0;e<6;e++){
    const int ia=c_be[2*e], ib=c_be[2*e+1];
    if (oc[ia]!=oc[ib]){
      const int p=vv[ia], q=vv[ib];
      const int lo = p<q?p:q, hi = p<q?q:p;
      const u32 off = bsum[lo>>10] + cntE[lo];
      const u32 slot = atomicAdd(&cur[lo],1u);
      const u32 idx = off + slot;
      if (idx < (u32)ecap) ehi[idx] = hi;
    }
  }
}

// ---------------- per-bucket sort+dedup FUSED with ucnt 256-segment scan ----------------
// 782 blocks; block b owns lo in [b*256, b*256+256)
__global__ void sort_dedup_scan(const u32* __restrict__ cnt, const u32* __restrict__ cntE,
    const u32* __restrict__ bsum, int* __restrict__ ehi,
    u32* __restrict__ ucnt, u32* __restrict__ ucnt_ex, u32* __restrict__ usum, int ecap)
{
  __shared__ u32 sh4[4];
  const int tid = threadIdx.x;
  const int lo = blockIdx.x*256 + tid;
  u32 u = 0;
  if (lo < NV){
    int n = (int)cnt[lo];
    const u32 off = bsum[lo>>10] + cntE[lo];
    long long rem = (long long)ecap - (long long)off;
    if (rem < 0) rem = 0;
    if ((long long)n > rem) n = (int)rem;
    int* b = ehi + off;
    for (int i=1;i<n;i++){
      const int key = b[i];
      int j=i-1;
      while (j>=0 && b[j] > key){ b[j+1]=b[j]; j--; }
      b[j+1]=key;
    }
    int uu=0; int prev=-1;
    for (int i=0;i<n;i++){
      const int x = b[i];
      if (x != prev){ b[uu]=x; uu++; prev=x; }
    }
    u = (u32)uu;
  }
  const u32 incl = block_scan_fast(u, sh4, tid);
  if (lo < NV){ ucnt[lo] = u; ucnt_ex[lo] = incl - u; }
  if (tid == 255) usum[blockIdx.x] = incl;
}

// ---------------- top-level scan of usum[782] -> exclusive, meta[3]=M ----------------
__global__ void scan_top2(u32* __restrict__ usum, u32* __restrict__ meta)
{
  __shared__ u32 sh4[4];
  const int tid = threadIdx.x;
  u32 v[4]; u32 tot = 0;
#pragma unroll
  for (int i=0;i<4;i++){
    const int idx = tid*4 + i;
    v[i] = (idx < 782) ? usum[idx] : 0u;
    tot += v[i];
  }
  const u32 incl = block_scan_fast(tot, sh4, tid);
  u32 run = incl - tot;
#pragma unroll
  for (int i=0;i<4;i++){
    const int idx = tid*4 + i;
    if (idx < 782) usum[idx] = run;
    run += v[i];
  }
  if (tid == 255) meta[3] = incl;
}

// ---------------- fused emit: blocks 0..781 verts; blocks 782..3906 faces ----------------
__global__ void emit_all(const int* __restrict__ tet, const float* __restrict__ pos,
    const float* __restrict__ sdf, const unsigned char* __restrict__ codes,
    const u32* __restrict__ tscan, const u64* __restrict__ tsumE, const u32* __restrict__ meta,
    const u32* __restrict__ ucnt, const u32* __restrict__ ucnt_ex, const u32* __restrict__ usum,
    const u32* __restrict__ cntE, const u32* __restrict__ bsum,
    const int* __restrict__ ehi, float* __restrict__ out, int out_size)
{
  const int tid = threadIdx.x;
  if (blockIdx.x < 782){
    const int lo = blockIdx.x*256 + tid;
    if (lo >= NV) return;
    const int u = (int)ucnt[lo];
    if (u == 0) return;
    const int* b = ehi + (bsum[lo>>10] + cntE[lo]);
    const u32 idbase = usum[lo>>8] + ucnt_ex[lo];
    const float s0 = sdf[lo];
    const float p0x = pos[3*lo], p0y = pos[3*lo+1], p0z = pos[3*lo+2];
    for (int j=0;j<u;j++){
      const int hi = b[j];
      const float s1 = sdf[hi];
      const float d = s0 - s1;
      const float vx = (p0x*(-s1) + pos[3*hi  ]*s0) / d;
      const float vy = (p0y*(-s1) + pos[3*hi+1]*s0) / d;
      const float vz = (p0z*(-s1) + pos[3*hi+2]*s0) / d;
      const long long w = 3ll*(long long)(idbase+(u32)j);
      if (w + 3 <= (long long)out_size){
        out[w]=vx; out[w+1]=vy; out[w+2]=vz;
      }
    }
  } else {
    const int t = (blockIdx.x - 782)*256 + tid;   // < 800000 exactly
    const int code = codes[t];
    const int nt = c_ntri[code];
    if (nt == 0) return;
    const u64 tb = tsumE[t>>8];
    const u32 ts = tscan[t];
    const u32 n1e = (u32)(tb & 0xffffffffull) + (ts & 0xffffu);
    const u32 n2e = (u32)(tb >> 32) + (ts >> 16);
    const u32 N1 = meta[0];
    const u32 M  = meta[3];
    const u32 fb = (nt==1) ? n1e : (N1 + 2u*n2e);
    const int4 v = *(const int4*)(&tet[4*t]);
    const int vv[4]={v.x,v.y,v.z,v.w};
    for (int r=0;r<nt;r++){
      for (int k=0;k<3;k++){
        const int e = c_tri[code][3*r+k];
        const int ia=c_be[2*e], ib=c_be[2*e+1];
        const int p=vv[ia], q=vv[ib];
        const int lo = p<q?p:q, hi = p<q?q:p;
        const int* b = ehi + (bsum[lo>>10] + cntE[lo]);
        const int u = (int)ucnt[lo];
        int id = -1;
        for (int j=0;j<u;j++){
          if (b[j]==hi){ id = (int)(usum[lo>>8] + ucnt_ex[lo]) + j; break; }
        }
        const long long w = 3ll*(long long)M + 3ll*(long long)(fb+(u32)r) + k;
        if (w < (long long)out_size && id >= 0) out[w] = (float)id;
      }
    }
  }
}

// ---------------- launch: 9 dispatches ----------------
extern "C" void kernel_launch(void* const* d_in, const int* in_sizes, int n_in,
                              void* d_out, int out_size, void* d_ws, size_t ws_size,
                              hipStream_t stream)
{
  (void)in_sizes; (void)n_in;
  const float* pos = (const float*)d_in[0];
  const int*   tet = (const int*)d_in[1];
  const float* w0 = (const float*)d_in[2];
  const float* b0 = (const float*)d_in[3];
  const float* w1 = (const float*)d_in[4];
  const float* b1 = (const float*)d_in[5];
  const float* w2 = (const float*)d_in[6];
  const float* b2 = (const float*)d_in[7];
  const float* w3 = (const float*)d_in[8];
  const float* b3 = (const float*)d_in[9];
  const float* wf = (const float*)d_in[10];
  const float* bf = (const float*)d_in[11];
  float* out = (float*)d_out;
  char* ws = (char*)d_ws;

  float*         sdf   = (float*)(ws + 0);               // 800000 B
  unsigned char* codes = (unsigned char*)(ws + 800000);  // 800000 B
  u32* cnt     = (u32*)(ws + 1600000);                   // 800000 B
  u32* cntE    = (u32*)(ws + 2400000);                   // 800000 B
  u32* ucnt    = (u32*)(ws + 3200000);                   // 800000 B
  u32* ucnt_ex = (u32*)(ws + 4000000);                   // 800000 B
  u32* cur     = (u32*)(ws + 4800000);                   // 800000 B
  u32* bsum    = (u32*)(ws + 5600000);                   // 1024 B (196 used)
  u32* usum    = (u32*)(ws + 5601024);                   // 4096 B (782 used)
  u32* meta    = (u32*)(ws + 5605120);                   // 64 B
  u32* tsum    = (u32*)(ws + 5605184);                   // 12800 B (3125 used)
  u64* tsumE   = (u64*)(ws + 5618048);                   // 25088 B (3125 used)
  u32* tscan   = (u32*)(ws + 5643136);                   // 3200000 B
  _Float16* wp = (_Float16*)(ws + 8843136);              // 819200 B
  int* ehi     = (int*)(ws + 9662336);
  long long avail = ((long long)ws_size - 9662336ll) / 4ll;
  if (avail > 2000000ll) avail = 2000000ll;
  if (avail < 0ll) avail = 0ll;
  const int ecap = (int)avail;

  split_weights<<<800,256,0,stream>>>(w0,w1,w2,w3,wp,cnt,cur);
  mlp_mfma<<<MBLK,512,0,stream>>>(pos,wp,b0,b1,b2,b3,wf,bf,sdf);

  tet_count<<<NBLK,256,0,stream>>>(tet,sdf,codes,tscan,tsum,cnt);
  scan_mid<<<197,256,0,stream>>>(cnt,cntE,bsum,tsum,tsumE,meta);    // meta[0]=N1, meta[1]=N2
  scan_top<<<1,256,0,stream>>>(bsum,meta,2);                        // bsum -> exclusive
  fill_edges<<<NBLK,256,0,stream>>>(tet,codes,cntE,bsum,cur,ehi,ecap);
  sort_dedup_scan<<<782,256,0,stream>>>(cnt,cntE,bsum,ehi,ucnt,ucnt_ex,usum,ecap);
  scan_top2<<<1,256,0,stream>>>(usum,meta);                         // usum -> exclusive, meta[3]=M
  emit_all<<<3907,256,0,stream>>>(tet,pos,sdf,codes,tscan,tsumE,meta,
                                  ucnt,ucnt_ex,usum,cntE,bsum,ehi,out,out_size);
}

// Round 10
// 607.207 us; speedup vs baseline: 1.7220x; 1.7220x over previous
//
#include <hip/hip_runtime.h>
#include <cstdint>
#include <cstddef>

#define NV 200000
#define NT 800000
#define ROWS 64
#define MBLK 3125   // 3125*64 = 200000 exactly
#define NBLK 3125   // 3125*256 = 800000 exactly (tet kernels)

typedef unsigned int u32;
typedef unsigned long long u64;

typedef __attribute__((ext_vector_type(8))) _Float16 half8;
typedef __attribute__((ext_vector_type(4))) float f32x4;
#define MFMA16F __builtin_amdgcn_mfma_f32_16x16x32_f16

// ---------------- marching-tets tables ----------------
__constant__ int c_tri[16][6] = {
  {-1,-1,-1,-1,-1,-1},{1,0,2,-1,-1,-1},{4,0,3,-1,-1,-1},{1,4,2,1,3,4},
  {3,1,5,-1,-1,-1},{2,3,0,2,5,3},{1,4,0,1,5,4},{4,2,5,-1,-1,-1},
  {4,5,2,-1,-1,-1},{4,1,0,4,5,1},{3,2,0,3,5,2},{1,3,5,-1,-1,-1},
  {4,1,2,4,3,1},{3,0,4,-1,-1,-1},{2,0,1,-1,-1,-1},{-1,-1,-1,-1,-1,-1}};
__constant__ int c_ntri[16] = {0,1,1,2,1,2,2,1,1,2,2,1,2,1,1,0};
__constant__ int c_be[12] = {0,1,0,2,0,3,1,2,1,3,2,3};

// ---------------- fp16 Dekker 2-way split: x ~= h + m*2^-11 ----------------
__device__ __forceinline__ void split2(float x, _Float16& h, _Float16& m){
  h = (_Float16)x;
  const float r = x - (float)h;
  m = (_Float16)(r * 2048.0f);
}

// ---------------- weight split prep + workspace zeroing (fused memsets) ----------------
__global__ void split_weights(const float* __restrict__ w0, const float* __restrict__ w1,
                              const float* __restrict__ w2, const float* __restrict__ w3,
                              _Float16* __restrict__ wp,
                              u32* __restrict__ cnt_z, u32* __restrict__ cur_z)
{
  const int idx = blockIdx.x*256 + threadIdx.x;   // 0..204799
  if (idx < NV){ cnt_z[idx] = 0u; cur_z[idx] = 0u; }
  int base, k, n, psz;
  float val;
  if (idx < 8192){                                  // layer0: K=27 padded to 32
    base = 0; psz = 8192; k = idx >> 8; n = idx & 255;
    val = (k < 27) ? w0[k*256 + n] : 0.f;
  } else {
    int r = idx - 8192;
    const int l = r >> 16;                          // 0..2 -> layers 1..3
    r &= 65535;
    k = r >> 8; n = r & 255; psz = 65536;
    base = 16384 + l*131072;
    const float* w = (l==0) ? w1 : (l==1) ? w2 : w3;
    val = w[k*256 + n];
  }
  _Float16 h, m; split2(val, h, m);
  const int c = k >> 5, kk = k & 31;
  const int off = (c*256 + n)*32 + kk;
  wp[base + off] = h;
  wp[base + psz + off] = m;
}

// ---------------- MFMA MLP (round-8 proven config: ROWS=64, lb(512,4), 2 blocks/CU, ~255 us)
// NOTE: gfx950 unified VGPR+AGPR file — this kernel uses 64 VGPR + 64 AGPR = 128 total,
// exactly the 4-wave/SIMD budget. lb(512,6) forces spill (round 9: 1.8 GB scratch traffic).
template<int NC, bool LAST>
__device__ __forceinline__ void layer_run(
    const _Float16* __restrict__ Wl, const float* __restrict__ Bv,
    const float* __restrict__ wfv,
    _Float16 (*Af)[ROWS][264], float (*part)[8],
    int lane, int wv)
{
  const int l15 = lane & 15, q = lane >> 4;
  const int col0 = wv * 32;
  f32x4 g0[4][2], g1[4][2];
#pragma unroll
  for (int i=0;i<4;i++)
#pragma unroll
    for (int j=0;j<2;j++){ g0[i][j] = (f32x4){0.f,0.f,0.f,0.f}; g1[i][j] = (f32x4){0.f,0.f,0.f,0.f}; }

  const _Float16* bp = Wl + (u32)((col0 + l15)*32 + q*8);
  half8 bA[2][2], bB[2][2];

  auto loadB = [&](int c, half8 (*dst)[2]){
#pragma unroll
    for (int p=0;p<2;p++)
#pragma unroll
      for (int nt=0;nt<2;nt++)
        dst[p][nt] = *(const half8*)(bp + (p*NC + c)*8192 + nt*512);
  };
  auto compute = [&](int c, const half8 (*bb)[2]){
#pragma unroll
    for (int mt=0;mt<4;mt++){
      const _Float16* ap = &Af[0][mt*16 + l15][c*32 + q*8];
      const half8 ah = *(const half8*)(ap);
      const half8 am = *(const half8*)(ap + ROWS*264);
#pragma unroll
      for (int nt=0;nt<2;nt++){
        g0[mt][nt] = MFMA16F(ah, bb[0][nt], g0[mt][nt], 0,0,0);   // h*h
        g1[mt][nt] = MFMA16F(ah, bb[1][nt], g1[mt][nt], 0,0,0);   // h*m'
        g1[mt][nt] = MFMA16F(am, bb[0][nt], g1[mt][nt], 0,0,0);   // m'*h
      }
    }
  };

  loadB(0, bA);
  if (NC == 1){
    compute(0, bA);
  } else {
#pragma unroll 1
    for (int ch=0; ch<NC/2; ch++){
      const int c0 = 2*ch;
      loadB(c0+1, bB);
      compute(c0, bA);
      if (c0+2 < NC) loadB(c0+2, bA);
      compute(c0+1, bB);
    }
  }
  __syncthreads();

  const float S = 4.8828125e-4f;         // 2^-11
  if (!LAST){
#pragma unroll
    for (int nt=0;nt<2;nt++){
      const int col = col0 + nt*16 + l15;
      const float bias = Bv[col];
#pragma unroll
      for (int mt=0;mt<4;mt++)
#pragma unroll
        for (int reg=0;reg<4;reg++){
          const int row = mt*16 + q*4 + reg;
          const float v = fmaxf(g0[mt][nt][reg] + S*g1[mt][nt][reg] + bias, 0.f);
          _Float16 h,m; split2(v,h,m);
          Af[0][row][col] = h; Af[1][row][col] = m;
        }
    }
  } else {
    float pr[4][4];
#pragma unroll
    for (int mt=0;mt<4;mt++)
#pragma unroll
      for (int reg=0;reg<4;reg++) pr[mt][reg] = 0.f;
#pragma unroll
    for (int nt=0;nt<2;nt++){
      const int col = col0 + nt*16 + l15;
      const float bias = Bv[col];
      const float w = wfv[col];
#pragma unroll
      for (int mt=0;mt<4;mt++)
#pragma unroll
        for (int reg=0;reg<4;reg++)
          pr[mt][reg] += fmaxf(g0[mt][nt][reg] + S*g1[mt][nt][reg] + bias, 0.f) * w;
    }
#pragma unroll
    for (int s=1;s<16;s<<=1)
#pragma unroll
      for (int mt=0;mt<4;mt++)
#pragma unroll
        for (int reg=0;reg<4;reg++)
          pr[mt][reg] += __shfl_xor(pr[mt][reg], s, 64);
    if (l15 == 0){
#pragma unroll
      for (int mt=0;mt<4;mt++)
#pragma unroll
        for (int reg=0;reg<4;reg++)
          part[mt*16 + q*4 + reg][wv] = pr[mt][reg];
    }
  }
  __syncthreads();
}

__global__ __launch_bounds__(512,4) void mlp_mfma(
    const float* __restrict__ pos, const _Float16* __restrict__ wp,
    const float* __restrict__ b0, const float* __restrict__ b1,
    const float* __restrict__ b2, const float* __restrict__ b3,
    const float* __restrict__ wf, const float* __restrict__ bf,
    float* __restrict__ sdf)
{
  __shared__ _Float16 Af[2][ROWS][264];    // 67,584 B
  __shared__ float part[ROWS][8];          // 2,048 B -> 69.6 KB = 2 blocks/CU
  const int tid = threadIdx.x;
  const int lane = tid & 63, wv = tid >> 6;
  const int row0 = blockIdx.x * ROWS;

#pragma unroll
  for (int it=0; it<4; it++){
    const int idx = it*512 + tid;          // 2048 = 64 rows x 32 k
    const int r = idx & 63, f = idx >> 6;
    float val = 0.f;
    if (f < 3){
      val = pos[(row0 + r)*3 + f];
    } else if (f < 27){
      const int g = (f-3)/6, rem = (f-3)%6;
      const int d = rem % 3;
      const float x = pos[(row0 + r)*3 + d];
      const float fr = (float)(1 << g) * 3.14159265358979323846f;
      val = (rem < 3) ? sinf(fr*x) : cosf(fr*x);
    }
    _Float16 h,m; split2(val,h,m);
    Af[0][r][f] = h; Af[1][r][f] = m;
  }
  __syncthreads();

  layer_run<1,false>(wp + 0,      b0, nullptr, Af, part, lane, wv);
  layer_run<8,false>(wp + 16384,  b1, nullptr, Af, part, lane, wv);
  layer_run<8,false>(wp + 147456, b2, nullptr, Af, part, lane, wv);
  layer_run<8,true >(wp + 278528, b3, wf,      Af, part, lane, wv);

  if (tid < ROWS){
    float s = 0.f;
#pragma unroll
    for (int w=0; w<8; w++) s += part[tid][w];
    sdf[row0 + tid] = s + bf[0];
  }
}

// ---------------- scan helpers ----------------
__device__ __forceinline__ u32 wave_scan_incl(u32 v, int lane){
#pragma unroll
  for (int s=1;s<64;s<<=1){
    const u32 y = __shfl_up(v, s, 64);
    if (lane >= s) v += y;
  }
  return v;
}
// 256-thread block scan via wave shuffles (1 internal barrier)
__device__ __forceinline__ u32 block_scan_fast(u32 v, u32* sh4, int tid){
  const int lane = tid & 63, wv = tid >> 6;
  const u32 incl = wave_scan_incl(v, lane);
  if (lane == 63) sh4[wv] = incl;
  __syncthreads();
  u32 base = 0;
#pragma unroll
  for (int w=0;w<3;w++) if (w < wv) base += sh4[w];
  return incl + base;
}
__device__ __forceinline__ u64 bscan_u64(u64 v, u64* sh, int tid){
  sh[tid]=v; __syncthreads();
#pragma unroll
  for (int s=1;s<256;s<<=1){
    const u64 y = (tid>=s) ? sh[tid-s] : 0ull;
    __syncthreads();
    sh[tid] += y;
    __syncthreads();
  }
  return sh[tid];
}
// in-block exclusive scan of bsum[196] (per-1024-segment totals) -> shb[196]
__device__ __forceinline__ void scan_bsum_lds(const u32* __restrict__ bsum, u32* shb,
                                              u32* sh4, int tid){
  const u32 v = (tid < 196) ? bsum[tid] : 0u;
  const u32 incl = block_scan_fast(v, sh4, tid);
  if (tid < 196) shb[tid] = incl - v;
  __syncthreads();
}

// ---------------- tet pass 1: codes, in-block stable (n1,n2) scan, bucket counts ----------------
__global__ void tet_count(const int* __restrict__ tet, const float* __restrict__ sdf,
    unsigned char* __restrict__ codes, u32* __restrict__ tscan, u32* __restrict__ tsum,
    u32* __restrict__ cnt)
{
  __shared__ u32 sh4[4];
  const int tid = threadIdx.x;
  const int t = blockIdx.x*256 + tid;
  const int4 v = *(const int4*)(&tet[4*t]);
  const int o0 = sdf[v.x] > 0.f;
  const int o1 = sdf[v.y] > 0.f;
  const int o2 = sdf[v.z] > 0.f;
  const int o3 = sdf[v.w] > 0.f;
  const int code = o0 | (o1<<1) | (o2<<2) | (o3<<3);
  codes[t] = (unsigned char)code;
  const int nt = c_ntri[code];
  if (nt > 0){
    const int vv[4] = {v.x, v.y, v.z, v.w};
    const int oc[4] = {o0,o1,o2,o3};
#pragma unroll
    for (int e=0;e<6;e++){
      const int ia = c_be[2*e], ib = c_be[2*e+1];
      if (oc[ia] != oc[ib]){
        const int p = vv[ia], q = vv[ib];
        const int lo = p<q ? p : q;
        atomicAdd(&cnt[lo], 1u);
      }
    }
  }
  const u32 my = (u32)(nt==1) | ((u32)(nt==2)<<16);
  const u32 incl = block_scan_fast(my, sh4, tid);
  tscan[t] = incl - my;
  if (tid == 255) tsum[blockIdx.x] = incl;
}

// ---------------- mid-level scans (fused): blocks 0..195 cnt-segments; block 196 tsum scan ----------------
__global__ void scan_mid(const u32* __restrict__ cnt, u32* __restrict__ cntE,
                         u32* __restrict__ bsum, const u32* __restrict__ tsum,
                         u64* __restrict__ tsumE, u32* __restrict__ meta)
{
  __shared__ u32 sh4[4];
  __shared__ u64 sh64[256];
  const int tid = threadIdx.x;
  if (blockIdx.x < 196){
    const int base = blockIdx.x*1024 + tid*4;
    u32 v[4]; u32 tot=0;
#pragma unroll
    for (int i=0;i<4;i++){
      const int idx = base+i;
      v[i] = (idx<NV) ? cnt[idx] : 0u;
      tot += v[i];
    }
    const u32 incl = block_scan_fast(tot, sh4, tid);
    u32 run = incl - tot;
#pragma unroll
    for (int i=0;i<4;i++){
      const int idx = base+i;
      if (idx<NV) cntE[idx] = run;
      run += v[i];
    }
    if (tid==255) bsum[blockIdx.x] = incl;
  } else {
    u64 loc[13]; u64 tot = 0ull;
#pragma unroll
    for (int i=0;i<13;i++){
      const int idx = tid*13 + i;
      const u32 p = (idx < NBLK) ? tsum[idx] : 0u;
      const u64 u = (u64)(p & 0xffffu) | ((u64)(p >> 16) << 32);
      loc[i] = u; tot += u;
    }
    const u64 incl = bscan_u64(tot, sh64, tid);
    u64 run = incl - tot;
#pragma unroll
    for (int i=0;i<13;i++){
      const int idx = tid*13 + i;
      if (idx < NBLK) tsumE[idx] = run;
      run += loc[i];
    }
    if (tid == 255){ meta[0] = (u32)(incl & 0xffffffffull); meta[1] = (u32)(incl >> 32); }
  }
}

// ---------------- fill pass (computes bsum exclusive scan in-block) ----------------
__global__ void fill_edges(const int* __restrict__ tet, const unsigned char* __restrict__ codes,
    const u32* __restrict__ cntE, const u32* __restrict__ bsum,
    u32* __restrict__ cur, int* __restrict__ ehi, int ecap)
{
  __shared__ u32 sh4[4];
  __shared__ u32 shb[196];
  const int tid = threadIdx.x;
  scan_bsum_lds(bsum, shb, sh4, tid);

  const int t = blockIdx.x*256 + tid;
  const int code = codes[t];
  if (c_ntri[code] == 0) return;
  const int4 v = *(const int4*)(&tet[4*t]);
  const int vv[4]={v.x,v.y,v.z,v.w};
  const int oc[4]={code&1,(code>>1)&1,(code>>2)&1,(code>>3)&1};
#pragma unroll
  for (int e=0;e<6;e++){
    const int ia=c_be[2*e], ib=c_be[2*e+1];
    if (oc[ia]!=oc[ib]){
      const int p=vv[ia], q=vv[ib];
      const int lo = p<q?p:q, hi = p<q?q:p;
      const u32 off = shb[lo>>10] + cntE[lo];
      const u32 slot = atomicAdd(&cur[lo],1u);
      const u32 idx = off + slot;
      if (idx < (u32)ecap) ehi[idx] = hi;
    }
  }
}

// ---------------- per-bucket sort+dedup FUSED with ucnt 256-segment scan ----------------
__global__ void sort_dedup_scan(const u32* __restrict__ cnt, const u32* __restrict__ cntE,
    const u32* __restrict__ bsum, int* __restrict__ ehi,
    u32* __restrict__ ucnt, u32* __restrict__ ucnt_ex, u32* __restrict__ usum, int ecap)
{
  __shared__ u32 sh4[4];
  __shared__ u32 shb[196];
  const int tid = threadIdx.x;
  scan_bsum_lds(bsum, shb, sh4, tid);

  const int lo = blockIdx.x*256 + tid;
  u32 u = 0;
  if (lo < NV){
    int n = (int)cnt[lo];
    const u32 off = shb[lo>>10] + cntE[lo];
    long long rem = (long long)ecap - (long long)off;
    if (rem < 0) rem = 0;
    if ((long long)n > rem) n = (int)rem;
    int* b = ehi + off;
    for (int i=1;i<n;i++){
      const int key = b[i];
      int j=i-1;
      while (j>=0 && b[j] > key){ b[j+1]=b[j]; j--; }
      b[j+1]=key;
    }
    int uu=0; int prev=-1;
    for (int i=0;i<n;i++){
      const int x = b[i];
      if (x != prev){ b[uu]=x; uu++; prev=x; }
    }
    u = (u32)uu;
  }
  __syncthreads();                      // protect sh4 reuse
  const u32 incl = block_scan_fast(u, sh4, tid);
  if (lo < NV){ ucnt[lo] = u; ucnt_ex[lo] = incl - u; }
  if (tid == 255) usum[blockIdx.x] = incl;
}

// ---------------- fused emit: blocks 0..781 verts; blocks 782..3906 faces ----------------
// Computes both top-level exclusive scans (bsum[196], usum[782]) in-block.
__global__ void emit_all(const int* __restrict__ tet, const float* __restrict__ pos,
    const float* __restrict__ sdf, const unsigned char* __restrict__ codes,
    const u32* __restrict__ tscan, const u64* __restrict__ tsumE, const u32* __restrict__ meta,
    const u32* __restrict__ ucnt, const u32* __restrict__ ucnt_ex, const u32* __restrict__ usum,
    const u32* __restrict__ cntE, const u32* __restrict__ bsum,
    const int* __restrict__ ehi, float* __restrict__ out, int out_size)
{
  __shared__ u32 sh4[4];
  __shared__ u32 shb[196];
  __shared__ u32 shu[784];
  __shared__ u32 shM;
  const int tid = threadIdx.x;
  scan_bsum_lds(bsum, shb, sh4, tid);
  {
    u32 v4[4]; u32 tot = 0;
#pragma unroll
    for (int i=0;i<4;i++){
      const u32 idx = tid*4 + i;
      v4[i] = (idx < 782) ? usum[idx] : 0u;
      tot += v4[i];
    }
    const u32 incl = block_scan_fast(tot, sh4, tid);
    u32 run = incl - tot;
#pragma unroll
    for (int i=0;i<4;i++){
      const u32 idx = tid*4 + i;
      if (idx < 782) shu[idx] = run;
      run += v4[i];
    }
    if (tid == 255) shM = incl;
    __syncthreads();
  }

  if (blockIdx.x < 782){
    const int lo = blockIdx.x*256 + tid;
    if (lo >= NV) return;
    const int u = (int)ucnt[lo];
    if (u == 0) return;
    const int* b = ehi + (shb[lo>>10] + cntE[lo]);
    const u32 idbase = shu[lo>>8] + ucnt_ex[lo];
    const float s0 = sdf[lo];
    const float p0x = pos[3*lo], p0y = pos[3*lo+1], p0z = pos[3*lo+2];
    for (int j=0;j<u;j++){
      const int hi = b[j];
      const float s1 = sdf[hi];
      const float d = s0 - s1;
      const float vx = (p0x*(-s1) + pos[3*hi  ]*s0) / d;
      const float vy = (p0y*(-s1) + pos[3*hi+1]*s0) / d;
      const float vz = (p0z*(-s1) + pos[3*hi+2]*s0) / d;
      const long long w = 3ll*(long long)(idbase+(u32)j);
      if (w + 3 <= (long long)out_size){
        out[w]=vx; out[w+1]=vy; out[w+2]=vz;
      }
    }
  } else {
    const int t = (blockIdx.x - 782)*256 + tid;   // < 800000 exactly
    const int code = codes[t];
    const int nt = c_ntri[code];
    if (nt == 0) return;
    const u64 tb = tsumE[t>>8];
    const u32 ts = tscan[t];
    const u32 n1e = (u32)(tb & 0xffffffffull) + (ts & 0xffffu);
    const u32 n2e = (u32)(tb >> 32) + (ts >> 16);
    const u32 N1 = meta[0];
    const u32 M  = shM;
    const u32 fb = (nt==1) ? n1e : (N1 + 2u*n2e);
    const int4 v = *(const int4*)(&tet[4*t]);
    const int vv[4]={v.x,v.y,v.z,v.w};
    for (int r=0;r<nt;r++){
      for (int k=0;k<3;k++){
        const int e = c_tri[code][3*r+k];
        const int ia=c_be[2*e], ib=c_be[2*e+1];
        const int p=vv[ia], q=vv[ib];
        const int lo = p<q?p:q, hi = p<q?q:p;
        const int* b = ehi + (shb[lo>>10] + cntE[lo]);
        const int u = (int)ucnt[lo];
        int id = -1;
        for (int j=0;j<u;j++){
          if (b[j]==hi){ id = (int)(shu[lo>>8] + ucnt_ex[lo]) + j; break; }
        }
        const long long w = 3ll*(long long)M + 3ll*(long long)(fb+(u32)r) + k;
        if (w < (long long)out_size && id >= 0) out[w] = (float)id;
      }
    }
  }
}

// ---------------- launch: 7 dispatches ----------------
extern "C" void kernel_launch(void* const* d_in, const int* in_sizes, int n_in,
                              void* d_out, int out_size, void* d_ws, size_t ws_size,
                              hipStream_t stream)
{
  (void)in_sizes; (void)n_in;
  const float* pos = (const float*)d_in[0];
  const int*   tet = (const int*)d_in[1];
  const float* w0 = (const float*)d_in[2];
  const float* b0 = (const float*)d_in[3];
  const float* w1 = (const float*)d_in[4];
  const float* b1 = (const float*)d_in[5];
  const float* w2 = (const float*)d_in[6];
  const float* b2 = (const float*)d_in[7];
  const float* w3 = (const float*)d_in[8];
  const float* b3 = (const float*)d_in[9];
  const float* wf = (const float*)d_in[10];
  const float* bf = (const float*)d_in[11];
  float* out = (float*)d_out;
  char* ws = (char*)d_ws;

  float*         sdf   = (float*)(ws + 0);               // 800000 B
  unsigned char* codes = (unsigned char*)(ws + 800000);  // 800000 B
  u32* cnt     = (u32*)(ws + 1600000);                   // 800000 B
  u32* cntE    = (u32*)(ws + 2400000);                   // 800000 B
  u32* ucnt    = (u32*)(ws + 3200000);                   // 800000 B
  u32* ucnt_ex = (u32*)(ws + 4000000);                   // 800000 B
  u32* cur     = (u32*)(ws + 4800000);                   // 800000 B
  u32* bsum    = (u32*)(ws + 5600000);                   // 1024 B (196 used)
  u32* usum    = (u32*)(ws + 5601024);                   // 4096 B (782 used)
  u32* meta    = (u32*)(ws + 5605120);                   // 64 B
  u32* tsum    = (u32*)(ws + 5605184);                   // 12800 B (3125 used)
  u64* tsumE   = (u64*)(ws + 5618048);                   // 25088 B (3125 used)
  u32* tscan   = (u32*)(ws + 5643136);                   // 3200000 B
  _Float16* wp = (_Float16*)(ws + 8843136);              // 819200 B
  int* ehi     = (int*)(ws + 9662336);
  long long avail = ((long long)ws_size - 9662336ll) / 4ll;
  if (avail > 2000000ll) avail = 2000000ll;
  if (avail < 0ll) avail = 0ll;
  const int ecap = (int)avail;

  split_weights<<<800,256,0,stream>>>(w0,w1,w2,w3,wp,cnt,cur);
  mlp_mfma<<<MBLK,512,0,stream>>>(pos,wp,b0,b1,b2,b3,wf,bf,sdf);

  tet_count<<<NBLK,256,0,stream>>>(tet,sdf,codes,tscan,tsum,cnt);
  scan_mid<<<197,256,0,stream>>>(cnt,cntE,bsum,tsum,tsumE,meta);    // meta[0]=N1, meta[1]=N2
  fill_edges<<<NBLK,256,0,stream>>>(tet,codes,cntE,bsum,cur,ehi,ecap);
  sort_dedup_scan<<<782,256,0,stream>>>(cnt,cntE,bsum,ehi,ucnt,ucnt_ex,usum,ecap);
  emit_all<<<3907,256,0,stream>>>(tet,pos,sdf,codes,tscan,tsumE,meta,
                                  ucnt,ucnt_ex,usum,cntE,bsum,ehi,out,out_size);
}

// Round 11
// 443.729 us; speedup vs baseline: 2.3564x; 1.3684x over previous
//
#include <hip/hip_runtime.h>
#include <cstdint>
#include <cstddef>

#define NV 200000
#define NT 800000
#define ROWS 64
#define MBLK 3125   // 3125*64 = 200000 exactly
#define NBLK 3125   // 3125*256 = 800000 exactly (tet kernels)
#define NSEGS 196   // ceil(200000/1024) lo-segments
#define PCAP 4096   // pairs per segment arena (expected ~300; ~200 sigma margin)

typedef unsigned int u32;
typedef unsigned long long u64;

typedef __attribute__((ext_vector_type(8))) _Float16 half8;
typedef __attribute__((ext_vector_type(4))) float f32x4;
#define MFMA16F __builtin_amdgcn_mfma_f32_16x16x32_f16

// ---------------- marching-tets tables ----------------
__constant__ int c_tri[16][6] = {
  {-1,-1,-1,-1,-1,-1},{1,0,2,-1,-1,-1},{4,0,3,-1,-1,-1},{1,4,2,1,3,4},
  {3,1,5,-1,-1,-1},{2,3,0,2,5,3},{1,4,0,1,5,4},{4,2,5,-1,-1,-1},
  {4,5,2,-1,-1,-1},{4,1,0,4,5,1},{3,2,0,3,5,2},{1,3,5,-1,-1,-1},
  {4,1,2,4,3,1},{3,0,4,-1,-1,-1},{2,0,1,-1,-1,-1},{-1,-1,-1,-1,-1,-1}};
__constant__ int c_ntri[16] = {0,1,1,2,1,2,2,1,1,2,2,1,2,1,1,0};
__constant__ int c_be[12] = {0,1,0,2,0,3,1,2,1,3,2,3};

// ---------------- fp16 Dekker 2-way split: x ~= h + m*2^-11 ----------------
__device__ __forceinline__ void split2(float x, _Float16& h, _Float16& m){
  h = (_Float16)x;
  const float r = x - (float)h;
  m = (_Float16)(r * 2048.0f);
}

// ---------------- weight split prep + segment-cursor zeroing ----------------
__global__ void split_weights(const float* __restrict__ w0, const float* __restrict__ w1,
                              const float* __restrict__ w2, const float* __restrict__ w3,
                              _Float16* __restrict__ wp, u32* __restrict__ segcur)
{
  const int idx = blockIdx.x*256 + threadIdx.x;   // 0..204799
  if (idx < 256) segcur[idx] = 0u;
  int base, k, n, psz;
  float val;
  if (idx < 8192){                                  // layer0: K=27 padded to 32
    base = 0; psz = 8192; k = idx >> 8; n = idx & 255;
    val = (k < 27) ? w0[k*256 + n] : 0.f;
  } else {
    int r = idx - 8192;
    const int l = r >> 16;                          // 0..2 -> layers 1..3
    r &= 65535;
    k = r >> 8; n = r & 255; psz = 65536;
    base = 16384 + l*131072;
    const float* w = (l==0) ? w1 : (l==1) ? w2 : w3;
    val = w[k*256 + n];
  }
  _Float16 h, m; split2(val, h, m);
  const int c = k >> 5, kk = k & 31;
  const int off = (c*256 + n)*32 + kk;
  wp[base + off] = h;
  wp[base + psz + off] = m;
}

// ---------------- MFMA MLP (proven config: ROWS=64, lb(512,4), 2 blocks/CU, ~255 us)
// NOTE: gfx950 unified VGPR+AGPR file — 64 VGPR + 64 AGPR = 128 total = the 4-wave/SIMD
// budget exactly. lb(512,6) forces scratch spill (round 9: 1.8 GB spill traffic). Keep 4.
template<int NC, bool LAST>
__device__ __forceinline__ void layer_run(
    const _Float16* __restrict__ Wl, const float* __restrict__ Bv,
    const float* __restrict__ wfv,
    _Float16 (*Af)[ROWS][264], float (*part)[8],
    int lane, int wv)
{
  const int l15 = lane & 15, q = lane >> 4;
  const int col0 = wv * 32;
  f32x4 g0[4][2], g1[4][2];
#pragma unroll
  for (int i=0;i<4;i++)
#pragma unroll
    for (int j=0;j<2;j++){ g0[i][j] = (f32x4){0.f,0.f,0.f,0.f}; g1[i][j] = (f32x4){0.f,0.f,0.f,0.f}; }

  const _Float16* bp = Wl + (u32)((col0 + l15)*32 + q*8);
  half8 bA[2][2], bB[2][2];

  auto loadB = [&](int c, half8 (*dst)[2]){
#pragma unroll
    for (int p=0;p<2;p++)
#pragma unroll
      for (int nt=0;nt<2;nt++)
        dst[p][nt] = *(const half8*)(bp + (p*NC + c)*8192 + nt*512);
  };
  auto compute = [&](int c, const half8 (*bb)[2]){
#pragma unroll
    for (int mt=0;mt<4;mt++){
      const _Float16* ap = &Af[0][mt*16 + l15][c*32 + q*8];
      const half8 ah = *(const half8*)(ap);
      const half8 am = *(const half8*)(ap + ROWS*264);
#pragma unroll
      for (int nt=0;nt<2;nt++){
        g0[mt][nt] = MFMA16F(ah, bb[0][nt], g0[mt][nt], 0,0,0);   // h*h
        g1[mt][nt] = MFMA16F(ah, bb[1][nt], g1[mt][nt], 0,0,0);   // h*m'
        g1[mt][nt] = MFMA16F(am, bb[0][nt], g1[mt][nt], 0,0,0);   // m'*h
      }
    }
  };

  loadB(0, bA);
  if (NC == 1){
    compute(0, bA);
  } else {
#pragma unroll 1
    for (int ch=0; ch<NC/2; ch++){
      const int c0 = 2*ch;
      loadB(c0+1, bB);
      compute(c0, bA);
      if (c0+2 < NC) loadB(c0+2, bA);
      compute(c0+1, bB);
    }
  }
  __syncthreads();

  const float S = 4.8828125e-4f;         // 2^-11
  if (!LAST){
#pragma unroll
    for (int nt=0;nt<2;nt++){
      const int col = col0 + nt*16 + l15;
      const float bias = Bv[col];
#pragma unroll
      for (int mt=0;mt<4;mt++)
#pragma unroll
        for (int reg=0;reg<4;reg++){
          const int row = mt*16 + q*4 + reg;
          const float v = fmaxf(g0[mt][nt][reg] + S*g1[mt][nt][reg] + bias, 0.f);
          _Float16 h,m; split2(v,h,m);
          Af[0][row][col] = h; Af[1][row][col] = m;
        }
    }
  } else {
    float pr[4][4];
#pragma unroll
    for (int mt=0;mt<4;mt++)
#pragma unroll
      for (int reg=0;reg<4;reg++) pr[mt][reg] = 0.f;
#pragma unroll
    for (int nt=0;nt<2;nt++){
      const int col = col0 + nt*16 + l15;
      const float bias = Bv[col];
      const float w = wfv[col];
#pragma unroll
      for (int mt=0;mt<4;mt++)
#pragma unroll
        for (int reg=0;reg<4;reg++)
          pr[mt][reg] += fmaxf(g0[mt][nt][reg] + S*g1[mt][nt][reg] + bias, 0.f) * w;
    }
#pragma unroll
    for (int s=1;s<16;s<<=1)
#pragma unroll
      for (int mt=0;mt<4;mt++)
#pragma unroll
        for (int reg=0;reg<4;reg++)
          pr[mt][reg] += __shfl_xor(pr[mt][reg], s, 64);
    if (l15 == 0){
#pragma unroll
      for (int mt=0;mt<4;mt++)
#pragma unroll
        for (int reg=0;reg<4;reg++)
          part[mt*16 + q*4 + reg][wv] = pr[mt][reg];
    }
  }
  __syncthreads();
}

__global__ __launch_bounds__(512,4) void mlp_mfma(
    const float* __restrict__ pos, const _Float16* __restrict__ wp,
    const float* __restrict__ b0, const float* __restrict__ b1,
    const float* __restrict__ b2, const float* __restrict__ b3,
    const float* __restrict__ wf, const float* __restrict__ bf,
    float* __restrict__ sdf)
{
  __shared__ _Float16 Af[2][ROWS][264];    // 67,584 B
  __shared__ float part[ROWS][8];          // 2,048 B -> 69.6 KB = 2 blocks/CU
  const int tid = threadIdx.x;
  const int lane = tid & 63, wv = tid >> 6;
  const int row0 = blockIdx.x * ROWS;

#pragma unroll
  for (int it=0; it<4; it++){
    const int idx = it*512 + tid;          // 2048 = 64 rows x 32 k
    const int r = idx & 63, f = idx >> 6;
    float val = 0.f;
    if (f < 3){
      val = pos[(row0 + r)*3 + f];
    } else if (f < 27){
      const int g = (f-3)/6, rem = (f-3)%6;
      const int d = rem % 3;
      const float x = pos[(row0 + r)*3 + d];
      const float fr = (float)(1 << g) * 3.14159265358979323846f;
      val = (rem < 3) ? sinf(fr*x) : cosf(fr*x);
    }
    _Float16 h,m; split2(val,h,m);
    Af[0][r][f] = h; Af[1][r][f] = m;
  }
  __syncthreads();

  layer_run<1,false>(wp + 0,      b0, nullptr, Af, part, lane, wv);
  layer_run<8,false>(wp + 16384,  b1, nullptr, Af, part, lane, wv);
  layer_run<8,false>(wp + 147456, b2, nullptr, Af, part, lane, wv);
  layer_run<8,true >(wp + 278528, b3, wf,      Af, part, lane, wv);

  if (tid < ROWS){
    float s = 0.f;
#pragma unroll
    for (int w=0; w<8; w++) s += part[tid][w];
    sdf[row0 + tid] = s + bf[0];
  }
}

// ---------------- scan helpers ----------------
__device__ __forceinline__ u32 wave_scan_incl(u32 v, int lane){
#pragma unroll
  for (int s=1;s<64;s<<=1){
    const u32 y = __shfl_up(v, s, 64);
    if (lane >= s) v += y;
  }
  return v;
}
__device__ __forceinline__ u32 block_scan_fast(u32 v, u32* sh4, int tid){
  const int lane = tid & 63, wv = tid >> 6;
  const u32 incl = wave_scan_incl(v, lane);
  if (lane == 63) sh4[wv] = incl;
  __syncthreads();
  u32 base = 0;
#pragma unroll
  for (int w=0;w<3;w++) if (w < wv) base += sh4[w];
  return incl + base;
}
__device__ __forceinline__ u64 bscan_u64(u64 v, u64* sh, int tid){
  sh[tid]=v; __syncthreads();
#pragma unroll
  for (int s=1;s<256;s<<=1){
    const u64 y = (tid>=s) ? sh[tid-s] : 0ull;
    __syncthreads();
    sh[tid] += y;
    __syncthreads();
  }
  return sh[tid];
}

// ---------------- K1: codes, in-block stable (n1,n2) scan, pair append ----------------
__global__ void tet_pairs(const int* __restrict__ tet, const float* __restrict__ sdf,
    unsigned char* __restrict__ codes, u32* __restrict__ tscan, u32* __restrict__ tsum,
    u32* __restrict__ segcur, u64* __restrict__ pairs)
{
  __shared__ u32 sh4[4];
  const int tid = threadIdx.x;
  const int t = blockIdx.x*256 + tid;
  const int4 v = *(const int4*)(&tet[4*t]);
  const int o0 = sdf[v.x] > 0.f;
  const int o1 = sdf[v.y] > 0.f;
  const int o2 = sdf[v.z] > 0.f;
  const int o3 = sdf[v.w] > 0.f;
  const int code = o0 | (o1<<1) | (o2<<2) | (o3<<3);
  codes[t] = (unsigned char)code;
  const int nt = c_ntri[code];
  if (nt > 0){
    const int vv[4] = {v.x, v.y, v.z, v.w};
    const int oc[4] = {o0,o1,o2,o3};
#pragma unroll
    for (int e=0;e<6;e++){
      const int ia = c_be[2*e], ib = c_be[2*e+1];
      if (oc[ia] != oc[ib]){
        const int p = vv[ia], q = vv[ib];
        const int lo = p<q ? p : q, hi = p<q ? q : p;
        const int seg = lo >> 10;
        const u32 slot = atomicAdd(&segcur[seg], 1u);
        if (slot < PCAP)
          pairs[(size_t)seg*PCAP + slot] = ((u64)(u32)lo << 32) | (u32)hi;
      }
    }
  }
  const u32 my = (u32)(nt==1) | ((u32)(nt==2)<<16);
  const u32 incl = block_scan_fast(my, sh4, tid);
  tscan[t] = incl - my;
  if (tid == 255) tsum[blockIdx.x] = incl;
}

// ---------------- K2: per-segment sort+dedup+index (blocks 0..195); tsum scan (block 196)
__global__ void seg_process(const u64* __restrict__ pairs_in, const u32* __restrict__ segcur,
    u64* __restrict__ uq, u32* __restrict__ ucnt, u32* __restrict__ ucnt_ex,
    u32* __restrict__ usum, const u32* __restrict__ tsum, u64* __restrict__ tsumE,
    u32* __restrict__ meta)
{
  const int tid = threadIdx.x;
  if (blockIdx.x == NSEGS){
    // scan tsum[3125] (packed u16 pairs) -> tsumE u64 exclusive (n1 lo32, n2 hi32)
    __shared__ u64 sh64[256];
    u64 loc[13]; u64 tot = 0ull;
#pragma unroll
    for (int i=0;i<13;i++){
      const int idx = tid*13 + i;
      const u32 p = (idx < NBLK) ? tsum[idx] : 0u;
      const u64 u = (u64)(p & 0xffffu) | ((u64)(p >> 16) << 32);
      loc[i] = u; tot += u;
    }
    const u64 incl = bscan_u64(tot, sh64, tid);
    u64 run = incl - tot;
#pragma unroll
    for (int i=0;i<13;i++){
      const int idx = tid*13 + i;
      if (idx < NBLK) tsumE[idx] = run;
      run += loc[i];
    }
    if (tid == 255){ meta[0] = (u32)(incl & 0xffffffffull); meta[1] = (u32)(incl >> 32); }
    return;
  }

  __shared__ u64 P[PCAP];         // 32 KB
  __shared__ u32 sh4[4];
  __shared__ u32 shbase;
  const int seg = blockIdx.x;
  int n = (int)segcur[seg];
  if (n > PCAP) n = PCAP;
  int np = 1; while (np < n) np <<= 1;

  for (int i=tid; i<np; i+=256)
    P[i] = (i < n) ? pairs_in[(size_t)seg*PCAP + i] : ~0ull;
  if (tid == 0) shbase = 0u;
  __syncthreads();

  // bitonic sort P[0..np)
  for (int k=2; k<=np; k<<=1){
    for (int j=k>>1; j>0; j>>=1){
      for (int i=tid; i<np; i+=256){
        const int ij = i ^ j;
        if (ij > i){
          const u64 a = P[i], b = P[ij];
          const bool up = ((i & k) == 0);
          if ((a > b) == up){ P[i] = b; P[ij] = a; }
        }
      }
      __syncthreads();
    }
  }

  // dedup + in-place left compaction (chunked; dest <= src, reads precede writes)
  for (int c=0; c<n; c+=256){
    const int i = c + tid;
    u64 key = 0ull; u32 f = 0u;
    if (i < n){
      key = P[i];
      f = (i == 0 || P[i] != P[i-1]) ? 1u : 0u;
    }
    __syncthreads();
    const u32 incl = block_scan_fast(f, sh4, tid);
    const u32 base = shbase;
    if (f) P[base + incl - 1u] = key;
    __syncthreads();
    if (tid == 255) shbase = base + incl;
    __syncthreads();
  }
  const int uc = (int)shbase;

  // write compacted unique (lo,hi) keys to global arena (overwrites pairs region)
  for (int i=tid; i<uc; i+=256) uq[(size_t)seg*PCAP + i] = P[i];

  // per-lo counts and segment-relative exclusive offsets via binary search in LDS
  const int lo0 = seg << 10;
  for (int c=0; c<1024; c+=256){
    const int lo = lo0 + c + tid;
    if (lo < NV){
      const u64 kl = (u64)(u32)lo << 32;
      const u64 kh = (u64)(u32)(lo+1) << 32;
      int a=0, b=uc;
      while (a < b){ const int m=(a+b)>>1; if (P[m] < kl) a=m+1; else b=m; }
      const int lb = a;
      b = uc;
      while (a < b){ const int m=(a+b)>>1; if (P[m] < kh) a=m+1; else b=m; }
      ucnt_ex[lo] = (u32)lb;
      ucnt[lo] = (u32)(a - lb);
    }
  }
  if (tid == 0) usum[seg] = (u32)uc;
}

// ---------------- K3: emit verts (blocks 0..195) + faces (blocks 196..3320) ----------------
__global__ void emit_all(const int* __restrict__ tet, const float* __restrict__ pos,
    const float* __restrict__ sdf, const unsigned char* __restrict__ codes,
    const u32* __restrict__ tscan, const u64* __restrict__ tsumE, const u32* __restrict__ meta,
    const u64* __restrict__ uq, const u32* __restrict__ ucnt, const u32* __restrict__ ucnt_ex,
    const u32* __restrict__ usum, float* __restrict__ out, int out_size)
{
  __shared__ u32 sh4[4];
  __shared__ u32 shu[NSEGS];
  __shared__ u32 shM;
  const int tid = threadIdx.x;
  {
    const u32 v = (tid < NSEGS) ? usum[tid] : 0u;
    const u32 incl = block_scan_fast(v, sh4, tid);
    if (tid < NSEGS) shu[tid] = incl - v;
    if (tid == NSEGS-1) shM = incl;
    __syncthreads();
  }

  if (blockIdx.x < NSEGS){
    const int seg = blockIdx.x;
    const int uc = (int)usum[seg];
    const u32 base = shu[seg];
    for (int i=tid; i<uc; i+=256){
      const u64 key = uq[(size_t)seg*PCAP + i];
      const int lo = (int)(key >> 32);
      const int hi = (int)(key & 0xffffffffull);
      const float s0 = sdf[lo], s1 = sdf[hi];
      const float d = s0 - s1;
      const float vx = (pos[3*lo  ]*(-s1) + pos[3*hi  ]*s0) / d;
      const float vy = (pos[3*lo+1]*(-s1) + pos[3*hi+1]*s0) / d;
      const float vz = (pos[3*lo+2]*(-s1) + pos[3*hi+2]*s0) / d;
      const long long w = 3ll*(long long)(base + (u32)i);
      if (w + 3 <= (long long)out_size){
        out[w] = vx; out[w+1] = vy; out[w+2] = vz;
      }
    }
  } else {
    const int t = (blockIdx.x - NSEGS)*256 + tid;   // 3125 blocks -> t < 800000 exactly
    const int code = codes[t];
    const int nt = c_ntri[code];
    if (nt == 0) return;
    const u64 tb = tsumE[t>>8];
    const u32 ts = tscan[t];
    const u32 n1e = (u32)(tb & 0xffffffffull) + (ts & 0xffffu);
    const u32 n2e = (u32)(tb >> 32) + (ts >> 16);
    const u32 N1 = meta[0];
    const u32 M  = shM;
    const u32 fb = (nt==1) ? n1e : (N1 + 2u*n2e);
    const int4 v = *(const int4*)(&tet[4*t]);
    const int vv[4] = {v.x, v.y, v.z, v.w};
    for (int r=0;r<nt;r++){
      for (int k=0;k<3;k++){
        const int e = c_tri[code][3*r+k];
        const int ia = c_be[2*e], ib = c_be[2*e+1];
        const int p = vv[ia], q = vv[ib];
        const int lo = p<q ? p : q, hi = p<q ? q : p;
        const int seg = lo >> 10;
        const u32 st = ucnt_ex[lo];
        const int u = (int)ucnt[lo];
        const u64* b = uq + (size_t)seg*PCAP + st;
        int id = -1;
        for (int j=0;j<u;j++){
          if ((int)(b[j] & 0xffffffffull) == hi){ id = (int)(shu[seg] + st) + j; break; }
        }
        const long long w = 3ll*(long long)M + 3ll*(long long)(fb + (u32)r) + k;
        if (w < (long long)out_size && id >= 0) out[w] = (float)id;
      }
    }
  }
}

// ---------------- launch: 5 dispatches ----------------
extern "C" void kernel_launch(void* const* d_in, const int* in_sizes, int n_in,
                              void* d_out, int out_size, void* d_ws, size_t ws_size,
                              hipStream_t stream)
{
  (void)in_sizes; (void)n_in; (void)ws_size;
  const float* pos = (const float*)d_in[0];
  const int*   tet = (const int*)d_in[1];
  const float* w0 = (const float*)d_in[2];
  const float* b0 = (const float*)d_in[3];
  const float* w1 = (const float*)d_in[4];
  const float* b1 = (const float*)d_in[5];
  const float* w2 = (const float*)d_in[6];
  const float* b2 = (const float*)d_in[7];
  const float* w3 = (const float*)d_in[8];
  const float* b3 = (const float*)d_in[9];
  const float* wf = (const float*)d_in[10];
  const float* bf = (const float*)d_in[11];
  float* out = (float*)d_out;
  char* ws = (char*)d_ws;

  float*         sdf   = (float*)(ws + 0);               // 800000 B
  unsigned char* codes = (unsigned char*)(ws + 800000);  // 800000 B
  u32* tscan   = (u32*)(ws + 1600000);                   // 3200000 B
  u32* tsum    = (u32*)(ws + 4800000);                   // 12800 B (3125 used)
  u64* tsumE   = (u64*)(ws + 4812800);                   // 25088 B (3125 used)
  u32* segcur  = (u32*)(ws + 4837888);                   // 1024 B (196 used)
  u32* usum    = (u32*)(ws + 4838912);                   // 1024 B
  u32* meta    = (u32*)(ws + 4839936);                   // 64 B
  u32* ucnt    = (u32*)(ws + 4840000);                   // 800000 B
  u32* ucnt_ex = (u32*)(ws + 5640000);                   // 800000 B
  _Float16* wp = (_Float16*)(ws + 6440000);              // 819200 B
  u64* pairs   = (u64*)(ws + 7259200);                   // 196*4096*8 = 6422528 B (reused as uq)
  // total ws: 13,681,728 B (< 17.6 MB proven available in prior rounds)

  split_weights<<<800,256,0,stream>>>(w0,w1,w2,w3,wp,segcur);
  mlp_mfma<<<MBLK,512,0,stream>>>(pos,wp,b0,b1,b2,b3,wf,bf,sdf);

  tet_pairs<<<NBLK,256,0,stream>>>(tet,sdf,codes,tscan,tsum,segcur,pairs);
  seg_process<<<NSEGS+1,256,0,stream>>>(pairs,segcur,pairs,ucnt,ucnt_ex,usum,tsum,tsumE,meta);
  emit_all<<<NSEGS+NBLK,256,0,stream>>>(tet,pos,sdf,codes,tscan,tsumE,meta,
                                        pairs,ucnt,ucnt_ex,usum,out,out_size);
}